// Round 1
// baseline (260.068 us; speedup 1.0000x reference)
//
#include <hip/hip_runtime.h>
#include <math.h>

#define FILTERS 8
#define NB 32
#define NT 16
#define NH 64
#define NW 64
#define NC 3
#define GATES 32   // 4*FILTERS

__device__ __forceinline__ float hard_sigmoid(float v) {
    return fminf(fmaxf(fmaf(0.2f, v, 0.5f), 0.0f), 1.0f);
}

// One thread per output pixel; computes all 32 gate channels, updates h,c.
__global__ __launch_bounds__(256) void convlstm_step(
    const float* __restrict__ x,     // (B,T,H,W,C)
    const float* __restrict__ Wx,    // (3,3,3,32)
    const float* __restrict__ Wh,    // (3,3,8,32)
    const float* __restrict__ bias,  // (32,)
    const float* __restrict__ h_in,  // (B,H,W,8)  (unused when first)
    float* __restrict__ h_out,       // (B,H,W,8)
    float* __restrict__ c_buf,       // (B,H,W,8) in-place
    int t, int first)
{
    int tid = blockIdx.x * blockDim.x + threadIdx.x;   // 0 .. B*H*W-1
    int xc = tid & (NW - 1);
    int yc = (tid >> 6) & (NH - 1);
    int bi = tid >> 12;

    float z[GATES];
    #pragma unroll
    for (int i = 0; i < GATES; ++i) z[i] = bias[i];

    const float* xt = x + (((size_t)bi * NT + t) * NH * NW) * NC;

    #pragma unroll
    for (int ky = 0; ky < 3; ++ky) {
        int yy = yc + ky - 1;
        if ((unsigned)yy >= NH) continue;
        #pragma unroll
        for (int kx = 0; kx < 3; ++kx) {
            int xx = xc + kx - 1;
            if ((unsigned)xx >= NW) continue;

            // input conv: 3 channels
            const float* xp = xt + (yy * NW + xx) * NC;
            float x0 = xp[0], x1 = xp[1], x2 = xp[2];
            const float* wx0 = Wx + ((ky * 3 + kx) * NC) * GATES;
            #pragma unroll
            for (int co = 0; co < GATES; ++co) {
                float acc = z[co];
                acc = fmaf(x0, wx0[co], acc);
                acc = fmaf(x1, wx0[GATES + co], acc);
                acc = fmaf(x2, wx0[2 * GATES + co], acc);
                z[co] = acc;
            }

            if (!first) {
                const float* hp = h_in + (((size_t)bi * NH + yy) * NW + xx) * FILTERS;
                float4 hv0 = *(const float4*)hp;
                float4 hv1 = *(const float4*)(hp + 4);
                float hv[8] = {hv0.x, hv0.y, hv0.z, hv0.w,
                               hv1.x, hv1.y, hv1.z, hv1.w};
                const float* wh0 = Wh + ((ky * 3 + kx) * FILTERS) * GATES;
                #pragma unroll
                for (int ci = 0; ci < FILTERS; ++ci) {
                    #pragma unroll
                    for (int co = 0; co < GATES; ++co)
                        z[co] = fmaf(hv[ci], wh0[ci * GATES + co], z[co]);
                }
            }
        }
    }

    size_t pix = (((size_t)bi * NH + yc) * NW + xc) * FILTERS;

    float c_old[8];
    if (first) {
        #pragma unroll
        for (int i = 0; i < 8; ++i) c_old[i] = 0.0f;
    } else {
        float4 ca = *(const float4*)(c_buf + pix);
        float4 cb = *(const float4*)(c_buf + pix + 4);
        c_old[0] = ca.x; c_old[1] = ca.y; c_old[2] = ca.z; c_old[3] = ca.w;
        c_old[4] = cb.x; c_old[5] = cb.y; c_old[6] = cb.z; c_old[7] = cb.w;
    }

    float hn[8], cn[8];
    #pragma unroll
    for (int f0 = 0; f0 < 8; ++f0) {
        float ig = hard_sigmoid(z[f0]);
        float fg = hard_sigmoid(z[8 + f0]);
        float gg = tanhf(z[16 + f0]);
        float og = hard_sigmoid(z[24 + f0]);
        float cc = fmaf(fg, c_old[f0], ig * gg);
        cn[f0] = cc;
        hn[f0] = og * tanhf(cc);
    }

    *(float4*)(c_buf + pix)     = make_float4(cn[0], cn[1], cn[2], cn[3]);
    *(float4*)(c_buf + pix + 4) = make_float4(cn[4], cn[5], cn[6], cn[7]);
    *(float4*)(h_out + pix)     = make_float4(hn[0], hn[1], hn[2], hn[3]);
    *(float4*)(h_out + pix + 4) = make_float4(hn[4], hn[5], hn[6], hn[7]);
}

// One block per batch element: logits = flat(h) @ W_out + b_out, then softmax.
__global__ __launch_bounds__(256) void head_kernel(
    const float* __restrict__ h,     // (B,H,W,8) -> (B, 32768)
    const float* __restrict__ Wout,  // (32768, 4)
    const float* __restrict__ bout,  // (4,)
    float* __restrict__ out)         // (B, 4)
{
    const int b = blockIdx.x;
    const int tid = threadIdx.x;
    const float* hb = h + (size_t)b * (NH * NW * FILTERS);

    float acc[4] = {0.f, 0.f, 0.f, 0.f};
    for (int i = tid; i < NH * NW * FILTERS; i += 256) {
        float hv = hb[i];
        float4 w = *(const float4*)(Wout + (size_t)i * 4);
        acc[0] = fmaf(hv, w.x, acc[0]);
        acc[1] = fmaf(hv, w.y, acc[1]);
        acc[2] = fmaf(hv, w.z, acc[2]);
        acc[3] = fmaf(hv, w.w, acc[3]);
    }

    #pragma unroll
    for (int j = 0; j < 4; ++j)
        #pragma unroll
        for (int off = 32; off >= 1; off >>= 1)
            acc[j] += __shfl_down(acc[j], off, 64);

    __shared__ float red[4][4];
    int lane = tid & 63, wv = tid >> 6;
    if (lane == 0) {
        #pragma unroll
        for (int j = 0; j < 4; ++j) red[wv][j] = acc[j];
    }
    __syncthreads();

    if (tid == 0) {
        float logit[4];
        #pragma unroll
        for (int j = 0; j < 4; ++j)
            logit[j] = red[0][j] + red[1][j] + red[2][j] + red[3][j] + bout[j];
        float m = fmaxf(fmaxf(logit[0], logit[1]), fmaxf(logit[2], logit[3]));
        float e[4], s = 0.f;
        #pragma unroll
        for (int j = 0; j < 4; ++j) { e[j] = expf(logit[j] - m); s += e[j]; }
        float inv = 1.0f / s;
        #pragma unroll
        for (int j = 0; j < 4; ++j) out[b * 4 + j] = e[j] * inv;
    }
}

extern "C" void kernel_launch(void* const* d_in, const int* in_sizes, int n_in,
                              void* d_out, int out_size, void* d_ws, size_t ws_size,
                              hipStream_t stream) {
    const float* x    = (const float*)d_in[0];
    const float* Wx   = (const float*)d_in[1];
    const float* Wh   = (const float*)d_in[2];
    const float* b    = (const float*)d_in[3];
    const float* Wout = (const float*)d_in[4];
    const float* bout = (const float*)d_in[5];
    float* out = (float*)d_out;

    const size_t state_elems = (size_t)NB * NH * NW * FILTERS;  // 1,048,576
    float* h0 = (float*)d_ws;
    float* h1 = h0 + state_elems;
    float* cb = h1 + state_elems;

    dim3 block(256);
    dim3 grid((NB * NH * NW) / 256);  // 512 blocks

    for (int t = 0; t < NT; ++t) {
        const float* hin = (t & 1) ? h0 : h1;   // t=0 ignores hin (first=1)
        float* hout      = (t & 1) ? h1 : h0;
        convlstm_step<<<grid, block, 0, stream>>>(x, Wx, Wh, b, hin, hout, cb,
                                                  t, (t == 0) ? 1 : 0);
    }
    // t = 15 wrote h1
    head_kernel<<<NB, block, 0, stream>>>(h1, Wout, bout, out);
}

// Round 2
// 223.186 us; speedup vs baseline: 1.1653x; 1.1653x over previous
//
#include <hip/hip_runtime.h>
#include <math.h>

#define FILTERS 8
#define NB 32
#define NT 16
#define NH 64
#define NW 64
#define NC 3
#define GATES 32   // 4*FILTERS

__device__ __forceinline__ float hard_sigmoid(float v) {
    return fminf(fmaxf(fmaf(0.2f, v, 0.5f), 0.0f), 1.0f);
}

// One thread per (pixel, filter-half); computes 4 filters = 16 gate channels.
// blockIdx.y = which half of the filters (0: f0..3, 1: f4..7) -> weight
// indices stay wave-uniform -> scalar loads.
__global__ __launch_bounds__(256) void convlstm_step(
    const float* __restrict__ x,     // (B,T,H,W,C)
    const float* __restrict__ Wx,    // (3,3,3,32)
    const float* __restrict__ Wh,    // (3,3,8,32)
    const float* __restrict__ bias,  // (32,)
    const float* __restrict__ h_in,  // (B,H,W,8)  (unused when first)
    float* __restrict__ h_out,       // (B,H,W,8)
    float* __restrict__ c_buf,       // (B,H,W,8) in-place
    int t, int first)
{
    const int tid = blockIdx.x * blockDim.x + threadIdx.x;   // 0 .. B*H*W-1
    const int f0  = blockIdx.y * 4;                          // filter base
    const int xc = tid & (NW - 1);
    const int yc = (tid >> 6) & (NH - 1);
    const int bi = tid >> 12;

    // z[g*4+fi] accumulates gate g (i,f,c,o) for filter f0+fi
    float z[16];
    #pragma unroll
    for (int g = 0; g < 4; ++g)
        #pragma unroll
        for (int fi = 0; fi < 4; ++fi)
            z[g * 4 + fi] = bias[g * 8 + f0 + fi];

    const float* xt = x + (((size_t)bi * NT + t) * NH * NW) * NC;

    #pragma unroll
    for (int ky = 0; ky < 3; ++ky) {
        int yy = yc + ky - 1;
        if ((unsigned)yy >= NH) continue;
        #pragma unroll
        for (int kx = 0; kx < 3; ++kx) {
            int xx = xc + kx - 1;
            if ((unsigned)xx >= NW) continue;

            const float* xp = xt + (yy * NW + xx) * NC;
            float x0 = xp[0], x1 = xp[1], x2 = xp[2];
            const float* wxp = Wx + ((ky * 3 + kx) * NC) * GATES + f0;
            #pragma unroll
            for (int g = 0; g < 4; ++g)
                #pragma unroll
                for (int fi = 0; fi < 4; ++fi) {
                    int co = g * 8 + fi;
                    float acc = z[g * 4 + fi];
                    acc = fmaf(x0, wxp[co], acc);
                    acc = fmaf(x1, wxp[GATES + co], acc);
                    acc = fmaf(x2, wxp[2 * GATES + co], acc);
                    z[g * 4 + fi] = acc;
                }

            if (!first) {
                const float* hp = h_in + (((size_t)bi * NH + yy) * NW + xx) * FILTERS;
                float4 hv0 = *(const float4*)hp;
                float4 hv1 = *(const float4*)(hp + 4);
                float hv[8] = {hv0.x, hv0.y, hv0.z, hv0.w,
                               hv1.x, hv1.y, hv1.z, hv1.w};
                const float* whp = Wh + ((ky * 3 + kx) * FILTERS) * GATES + f0;
                #pragma unroll
                for (int ci = 0; ci < FILTERS; ++ci)
                    #pragma unroll
                    for (int g = 0; g < 4; ++g)
                        #pragma unroll
                        for (int fi = 0; fi < 4; ++fi)
                            z[g * 4 + fi] = fmaf(hv[ci], whp[ci * GATES + g * 8 + fi],
                                                 z[g * 4 + fi]);
            }
        }
    }

    const size_t pix = (((size_t)bi * NH + yc) * NW + xc) * FILTERS + f0;

    float c_old[4];
    if (first) {
        #pragma unroll
        for (int i = 0; i < 4; ++i) c_old[i] = 0.0f;
    } else {
        float4 ca = *(const float4*)(c_buf + pix);
        c_old[0] = ca.x; c_old[1] = ca.y; c_old[2] = ca.z; c_old[3] = ca.w;
    }

    float hn[4], cn[4];
    #pragma unroll
    for (int fi = 0; fi < 4; ++fi) {
        float ig = hard_sigmoid(z[0 * 4 + fi]);
        float fg = hard_sigmoid(z[1 * 4 + fi]);
        float gg = tanhf(z[2 * 4 + fi]);
        float og = hard_sigmoid(z[3 * 4 + fi]);
        float cc = fmaf(fg, c_old[fi], ig * gg);
        cn[fi] = cc;
        hn[fi] = og * tanhf(cc);
    }

    *(float4*)(c_buf + pix) = make_float4(cn[0], cn[1], cn[2], cn[3]);
    *(float4*)(h_out + pix) = make_float4(hn[0], hn[1], hn[2], hn[3]);
}

// Stage 1: 512 blocks (32 batches x 16 chunks); each reduces 2048 elements.
__global__ __launch_bounds__(256) void head_partial(
    const float* __restrict__ h,     // (B, 32768)
    const float* __restrict__ Wout,  // (32768, 4)
    float* __restrict__ partial)     // (B*16, 4)
{
    const int b = blockIdx.x >> 4;
    const int chunk = blockIdx.x & 15;
    const int tid = threadIdx.x;
    const float* hb = h + (size_t)b * 32768 + chunk * 2048;
    const float* wb = Wout + (size_t)(chunk * 2048) * 4;

    float acc[4] = {0.f, 0.f, 0.f, 0.f};
    #pragma unroll
    for (int it = 0; it < 8; ++it) {
        int i = it * 256 + tid;
        float hv = hb[i];
        float4 w = *(const float4*)(wb + (size_t)i * 4);
        acc[0] = fmaf(hv, w.x, acc[0]);
        acc[1] = fmaf(hv, w.y, acc[1]);
        acc[2] = fmaf(hv, w.z, acc[2]);
        acc[3] = fmaf(hv, w.w, acc[3]);
    }

    #pragma unroll
    for (int j = 0; j < 4; ++j)
        #pragma unroll
        for (int off = 32; off >= 1; off >>= 1)
            acc[j] += __shfl_down(acc[j], off, 64);

    __shared__ float red[4][4];
    int lane = tid & 63, wv = tid >> 6;
    if (lane == 0) {
        #pragma unroll
        for (int j = 0; j < 4; ++j) red[wv][j] = acc[j];
    }
    __syncthreads();
    if (tid == 0) {
        #pragma unroll
        for (int j = 0; j < 4; ++j)
            partial[(size_t)blockIdx.x * 4 + j] =
                red[0][j] + red[1][j] + red[2][j] + red[3][j];
    }
}

// Stage 2: one block; thread b sums 16 partials, softmax, writes out.
__global__ __launch_bounds__(64) void head_finish(
    const float* __restrict__ partial,  // (B*16, 4)
    const float* __restrict__ bout,     // (4,)
    float* __restrict__ out)            // (B, 4)
{
    int b = threadIdx.x;
    if (b >= NB) return;
    float logit[4] = {bout[0], bout[1], bout[2], bout[3]};
    #pragma unroll
    for (int k = 0; k < 16; ++k) {
        const float* p = partial + (size_t)(b * 16 + k) * 4;
        logit[0] += p[0]; logit[1] += p[1]; logit[2] += p[2]; logit[3] += p[3];
    }
    float m = fmaxf(fmaxf(logit[0], logit[1]), fmaxf(logit[2], logit[3]));
    float e[4], s = 0.f;
    #pragma unroll
    for (int j = 0; j < 4; ++j) { e[j] = expf(logit[j] - m); s += e[j]; }
    float inv = 1.0f / s;
    #pragma unroll
    for (int j = 0; j < 4; ++j) out[b * 4 + j] = e[j] * inv;
}

extern "C" void kernel_launch(void* const* d_in, const int* in_sizes, int n_in,
                              void* d_out, int out_size, void* d_ws, size_t ws_size,
                              hipStream_t stream) {
    const float* x    = (const float*)d_in[0];
    const float* Wx   = (const float*)d_in[1];
    const float* Wh   = (const float*)d_in[2];
    const float* b    = (const float*)d_in[3];
    const float* Wout = (const float*)d_in[4];
    const float* bout = (const float*)d_in[5];
    float* out = (float*)d_out;

    const size_t state_elems = (size_t)NB * NH * NW * FILTERS;  // 1,048,576
    float* h0 = (float*)d_ws;
    float* h1 = h0 + state_elems;
    float* cb = h1 + state_elems;
    float* partial = cb + state_elems;   // 512*4 floats

    dim3 block(256);
    dim3 grid((NB * NH * NW) / 256, 2);  // 512 x 2 = 1024 blocks

    for (int t = 0; t < NT; ++t) {
        const float* hin = (t & 1) ? h0 : h1;   // t=0 ignores hin (first=1)
        float* hout      = (t & 1) ? h1 : h0;
        convlstm_step<<<grid, block, 0, stream>>>(x, Wx, Wh, b, hin, hout, cb,
                                                  t, (t == 0) ? 1 : 0);
    }
    // t = 15 wrote h1
    head_partial<<<512, 256, 0, stream>>>(h1, Wout, partial);
    head_finish<<<1, 64, 0, stream>>>(partial, bout, out);
}